// Round 5
// baseline (869.334 us; speedup 1.0000x reference)
//
#include <hip/hip_runtime.h>

#define S_LEN 2048
#define D_DIM 128
#define BM 128   // q-rows per block
#define BK 64    // t-chunk per iter
#define NIT (S_LEN / BK)
#define LQ 136   // K/Q LDS row stride (bf16 elems), 272B, 16B-aligned
#define LV 72    // Vt LDS row stride (bf16 elems), 144B, 16B-aligned
#define KS_E (BK * LQ)     // 8704 elems
#define VT_E (D_DIM * LV)  // 9216 elems -> total 35840 B; 2 blocks/CU easily

typedef __attribute__((ext_vector_type(8))) short bf16x8;
typedef __attribute__((ext_vector_type(4))) float f32x4;
typedef __attribute__((ext_vector_type(4))) int i32x4;

__device__ __forceinline__ unsigned rnd16(float x) {
    union { float f; unsigned u; } c; c.f = x;
    return c.u + 0x8000u;  // round-half-away; abs err <= 1ulp bf16
}
__device__ __forceinline__ unsigned pack2(float lo, float hi) {
    return __builtin_amdgcn_perm(rnd16(hi), rnd16(lo), 0x07060302);
}

// 512 blocks x 512 threads (8 waves). Block = 128 q-rows of one (b,h);
// wave w owns 16 q-rows. Single-buffered K/V LDS (35.8 KB) -> 2 blocks/CU
// = 16 waves/CU = 4 waves/SIMD (2x R2). Q in registers. V prefetched one
// phase ahead (16 VGPRs); mask loaded at gemm-phase top (consumed after
// S-gemm). P redistributed S->O layout via ds_bpermute (no LDS, no barrier).
__global__ __launch_bounds__(512, 4)
void fused_qkmv(const float* __restrict__ q, const float* __restrict__ k,
                const float* __restrict__ v, const float* __restrict__ mask,
                float* __restrict__ out) {
    __shared__ __align__(16) unsigned short smem[KS_E + VT_E];
    // Ks = smem[0..KS_E), Vt = smem[KS_E..). Prologue overlays Q (17408 elems) over smem.

    const int tid  = threadIdx.x;
    const int lane = tid & 63;
    const int w    = tid >> 6;   // 0..7: s-rows 16w..16w+15
    const int l15  = lane & 15;
    const int qd   = lane >> 4;

    const int bh = blockIdx.x >> 4;
    const int s0 = (blockIdx.x & 15) * BM;

    const float* qp = q + (size_t)bh * S_LEN * D_DIM;
    const float* kp = k + (size_t)bh * S_LEN * D_DIM;
    const float* vp = v + (size_t)bh * S_LEN * D_DIM;
    const float* mp = mask + (size_t)bh * S_LEN * S_LEN;
    float*       op = out + (size_t)bh * S_LEN * D_DIM;

    // staging maps (512 threads)
    const int kr  = tid >> 3;          // K/Q row 0..63
    const int kc0 = (tid & 7) * 16;    // 16 consecutive floats
    const int tg  = (tid & 15) * 4;    // V: 4 t-rows
    const int dg  = (tid >> 4) * 4;    // V: 4 d-cols

    // ---- prologue: issue V(0) loads, stage Q -> LDS overlay, grab qf ----
    float4 vf[4];
#pragma unroll
    for (int r = 0; r < 4; ++r)
        vf[r] = *(const float4*)(vp + (size_t)(tg + r) * D_DIM + dg);

#pragma unroll
    for (int p = 0; p < 2; ++p) {
        const int row = 64 * p + kr;
        float4 f0 = *(const float4*)(qp + (size_t)(s0 + row) * D_DIM + kc0);
        float4 f1 = *(const float4*)(qp + (size_t)(s0 + row) * D_DIM + kc0 + 4);
        float4 f2 = *(const float4*)(qp + (size_t)(s0 + row) * D_DIM + kc0 + 8);
        float4 f3 = *(const float4*)(qp + (size_t)(s0 + row) * D_DIM + kc0 + 12);
        uint2 wv;
        wv.x = pack2(f0.x, f0.y); wv.y = pack2(f0.z, f0.w);
        *(uint2*)&smem[row * LQ + kc0] = wv;
        wv.x = pack2(f1.x, f1.y); wv.y = pack2(f1.z, f1.w);
        *(uint2*)&smem[row * LQ + kc0 + 4] = wv;
        wv.x = pack2(f2.x, f2.y); wv.y = pack2(f2.z, f2.w);
        *(uint2*)&smem[row * LQ + kc0 + 8] = wv;
        wv.x = pack2(f3.x, f3.y); wv.y = pack2(f3.z, f3.w);
        *(uint2*)&smem[row * LQ + kc0 + 12] = wv;
    }
    __syncthreads();
    bf16x8 qf[4];  // B-operand frags for wave's 16 s-rows
#pragma unroll
    for (int kc = 0; kc < 4; ++kc)
        qf[kc] = *(const bf16x8*)&smem[(16 * w + l15) * LQ + kc * 32 + qd * 8];
    __syncthreads();

    f32x4 acc_o[8];
#pragma unroll
    for (int j = 0; j < 8; ++j) acc_o[j] = (f32x4){0.f, 0.f, 0.f, 0.f};

    // bpermute quad-exchange addresses (validated R2)
    const int a0 = ((2 * (qd & 1)) * 16 + l15) * 4;
    const int a1 = a0 + 64;
    const bool hi = (qd >= 2);

    for (int it = 0; it < NIT; ++it) {
        const int t0 = it * BK;

        // ---- stage phase: issue K loads, write V (no wait), pack K ----
        float4 kf0 = *(const float4*)(kp + (size_t)(t0 + kr) * D_DIM + kc0);
        float4 kf1 = *(const float4*)(kp + (size_t)(t0 + kr) * D_DIM + kc0 + 4);
        float4 kf2 = *(const float4*)(kp + (size_t)(t0 + kr) * D_DIM + kc0 + 8);
        float4 kf3 = *(const float4*)(kp + (size_t)(t0 + kr) * D_DIM + kc0 + 12);
#pragma unroll
        for (int i = 0; i < 4; ++i) {
            uint2 wv;
            wv.x = pack2(((const float*)&vf[0])[i], ((const float*)&vf[1])[i]);
            wv.y = pack2(((const float*)&vf[2])[i], ((const float*)&vf[3])[i]);
            *(uint2*)&smem[KS_E + (dg + i) * LV + tg] = wv;
        }
        {
            uint2 wv;
            wv.x = pack2(kf0.x, kf0.y); wv.y = pack2(kf0.z, kf0.w);
            *(uint2*)&smem[kr * LQ + kc0] = wv;
            wv.x = pack2(kf1.x, kf1.y); wv.y = pack2(kf1.z, kf1.w);
            *(uint2*)&smem[kr * LQ + kc0 + 4] = wv;
            wv.x = pack2(kf2.x, kf2.y); wv.y = pack2(kf2.z, kf2.w);
            *(uint2*)&smem[kr * LQ + kc0 + 8] = wv;
            wv.x = pack2(kf3.x, kf3.y); wv.y = pack2(kf3.z, kf3.w);
            *(uint2*)&smem[kr * LQ + kc0 + 12] = wv;
        }
        __syncthreads();

        // ---- gemm phase ----
        // mask for this iter (consumed after S-gemm: ~400cyc window)
        float4 mreg[4];
        {
            const float* mb = mp + (size_t)(s0 + 16 * w + l15) * S_LEN + t0 + 4 * qd;
#pragma unroll
            for (int ti = 0; ti < 4; ++ti)
                mreg[ti] = *(const float4*)(mb + ti * 16);
        }

        // S^T = K·Q^T
        f32x4 acc_s[4];
#pragma unroll
        for (int i = 0; i < 4; ++i) acc_s[i] = (f32x4){0.f, 0.f, 0.f, 0.f};
#pragma unroll
        for (int kc = 0; kc < 4; ++kc) {
            const int ko = kc * 32 + qd * 8;
            bf16x8 af[4];
#pragma unroll
            for (int ti = 0; ti < 4; ++ti)
                af[ti] = *(const bf16x8*)&smem[(16 * ti + l15) * LQ + ko];
#pragma unroll
            for (int ti = 0; ti < 4; ++ti)
                acc_s[ti] = __builtin_amdgcn_mfma_f32_16x16x32_bf16(
                    af[ti], qf[kc], acc_s[ti], 0, 0, 0);
        }

        // prefetch V(it+1): in flight across P-pack/bperm/O-gemm/barrier
        if (it + 1 < NIT) {
            const int tn = t0 + BK;
#pragma unroll
            for (int r = 0; r < 4; ++r)
                vf[r] = *(const float4*)(vp + (size_t)(tn + tg + r) * D_DIM + dg);
        }

        // P = S^T ∘ mask -> packed bf16 (t = 16ti + 4qd + {0..3} per lane)
        int pu[4][2];
#pragma unroll
        for (int ti = 0; ti < 4; ++ti) {
            f32x4 sv = acc_s[ti];
            float4 m = mreg[ti];
            pu[ti][0] = (int)pack2(sv[0] * m.x, sv[1] * m.y);
            pu[ti][1] = (int)pack2(sv[2] * m.z, sv[3] * m.w);
        }

        // quad-exchange + O += P·V
#pragma unroll
        for (int kc2 = 0; kc2 < 2; ++kc2) {
            const int tA = 2 * kc2, tB = 2 * kc2 + 1;
            int w0a = __builtin_amdgcn_ds_bpermute(a0, pu[tA][0]);
            int w0b = __builtin_amdgcn_ds_bpermute(a0, pu[tB][0]);
            int w1a = __builtin_amdgcn_ds_bpermute(a0, pu[tA][1]);
            int w1b = __builtin_amdgcn_ds_bpermute(a0, pu[tB][1]);
            int w2a = __builtin_amdgcn_ds_bpermute(a1, pu[tA][0]);
            int w2b = __builtin_amdgcn_ds_bpermute(a1, pu[tB][0]);
            int w3a = __builtin_amdgcn_ds_bpermute(a1, pu[tA][1]);
            int w3b = __builtin_amdgcn_ds_bpermute(a1, pu[tB][1]);
            union { i32x4 i; bf16x8 b; } u;
            u.i = (i32x4){hi ? w0b : w0a, hi ? w1b : w1a,
                          hi ? w2b : w2a, hi ? w3b : w3a};
            const int ko = kc2 * 32 + qd * 8;
#pragma unroll
            for (int dj = 0; dj < 8; ++dj) {
                bf16x8 bv = *(const bf16x8*)&smem[KS_E + (16 * dj + l15) * LV + ko];
                acc_o[dj] = __builtin_amdgcn_mfma_f32_16x16x32_bf16(
                    u.b, bv, acc_o[dj], 0, 0, 0);
            }
        }

        __syncthreads();  // all reads of Ks/Vt done before next stage
    }

    // ---- epilogue: rows s0+16w+4qd+r, cols 16dj+l15 ----
#pragma unroll
    for (int dj = 0; dj < 8; ++dj)
#pragma unroll
        for (int r = 0; r < 4; ++r) {
            const int srow = s0 + 16 * w + 4 * qd + r;
            op[(size_t)srow * D_DIM + 16 * dj + l15] = acc_o[dj][r];
        }
}

extern "C" void kernel_launch(void* const* d_in, const int* in_sizes, int n_in,
                              void* d_out, int out_size, void* d_ws, size_t ws_size,
                              hipStream_t stream) {
    const float* q = (const float*)d_in[0];
    const float* k = (const float*)d_in[1];
    const float* v = (const float*)d_in[2];
    const float* m = (const float*)d_in[3];
    float* out = (float*)d_out;
    // 32 heads x 16 q-tiles = 512 blocks of 512 threads; 2 blocks/CU
    fused_qkmv<<<dim3(512), dim3(512), 0, stream>>>(q, k, v, m, out);
}

// Round 6
// 798.788 us; speedup vs baseline: 1.0883x; 1.0883x over previous
//
#include <hip/hip_runtime.h>
#include <stdint.h>

#define S_LEN 2048
#define D_DIM 128
#define BK 64
#define NIT (S_LEN / BK)
#define KIMG_BYTES (32u * 2048u * 256u)   // 16.78 MB bf16 K images (swizzled)
// Vt images: 32 heads x 32 tiles x 16384 B = 16.78 MB, after KIMG in ws

typedef __attribute__((ext_vector_type(8))) short bf16x8;
typedef __attribute__((ext_vector_type(4))) float f32x4;
typedef __attribute__((ext_vector_type(4))) int i32x4;

__device__ __forceinline__ unsigned rnd16(float x) {
    union { float f; unsigned u; } c; c.f = x;
    return c.u + 0x8000u;
}
__device__ __forceinline__ unsigned pack2(float lo, float hi) {
    return __builtin_amdgcn_perm(rnd16(hi), rnd16(lo), 0x07060302);
}

__device__ __forceinline__ void async_cp16(const void* g, void* l) {
    __builtin_amdgcn_global_load_lds(
        (const __attribute__((address_space(1))) unsigned int*)g,
        (__attribute__((address_space(3))) unsigned int*)l, 16, 0, 0);
}

// ---- prep: K -> bf16 swizzled image; V -> V^T bf16 tiled+swizzled image ----
// K image: per head, 2048 rows x 16 x 16B blocks; block cb stored at cb^(t&15).
// Vt image: per (head, t-chunk64): 128 d-rows x 8 x 16B blocks (t ascending);
//           block cb stored at cb^(d&7). Tiles contiguous (16 KB each).
__global__ __launch_bounds__(256)
void prep(const float* __restrict__ k, const float* __restrict__ v,
          unsigned char* __restrict__ kimg, unsigned char* __restrict__ vimg) {
    if (blockIdx.x < 4096) {
        const unsigned g = blockIdx.x * 256 + threadIdx.x;
        const int cb = g & 15, t = (g >> 4) & 2047, head = g >> 15;
        const float* src = k + ((size_t)head * 2048 + t) * 128 + cb * 8;
        float4 f0 = *(const float4*)src, f1 = *(const float4*)(src + 4);
        uint4 u;
        u.x = pack2(f0.x, f0.y); u.y = pack2(f0.z, f0.w);
        u.z = pack2(f1.x, f1.y); u.w = pack2(f1.z, f1.w);
        *(uint4*)(kimg + ((size_t)(head * 2048 + t) * 16 + (cb ^ (t & 15))) * 16) = u;
    } else {
        const int b = blockIdx.x - 4096;  // 0..1023 = (head, chunk)
        const int head = b >> 5, it = b & 31;
        const int tid = threadIdx.x;
        const int tg = (tid & 15) * 4, dg = (tid >> 4) * 8;
        const float* src = v + (size_t)head * 2048 * 128 + (size_t)(it * 64 + tg) * 128;
        float4 va[4], vb4[4];
#pragma unroll
        for (int r = 0; r < 4; ++r) {
            va[r]  = *(const float4*)(src + r * 128 + dg);
            vb4[r] = *(const float4*)(src + r * 128 + dg + 4);
        }
        unsigned char* dst = vimg + ((size_t)head * 32 + it) * 16384;
        const int half = (tg & 4) * 2;  // which 8B of the 16B block
#pragma unroll
        for (int i = 0; i < 4; ++i) {
            const int d = dg + i;
            uint2 wv;
            wv.x = pack2(((const float*)&va[0])[i], ((const float*)&va[1])[i]);
            wv.y = pack2(((const float*)&va[2])[i], ((const float*)&va[3])[i]);
            *(uint2*)(dst + d * 128 + (((tg >> 3) ^ (d & 7)) * 16) + half) = wv;
            const int d2 = dg + 4 + i;
            uint2 w2;
            w2.x = pack2(((const float*)&vb4[0])[i], ((const float*)&vb4[1])[i]);
            w2.y = pack2(((const float*)&vb4[2])[i], ((const float*)&vb4[3])[i]);
            *(uint2*)(dst + d2 * 128 + (((tg >> 3) ^ (d2 & 7)) * 16) + half) = w2;
        }
    }
}

// ---- main: 512 blocks x 256 thr (4 waves). Block = 128 q-rows of one head.
// Wave owns 32 s-rows. K/Vt tiles DMA'd (global_load_lds x16B) into a 2x32KB
// double buffer (64 KB -> 2 blocks/CU). One barrier/iter. Mask prefetched a
// full iter ahead. P exchanged S->O layout via ds_bpermute (R2-validated).
__global__ __launch_bounds__(256, 2)
void fused_main(const float* __restrict__ q, const float* __restrict__ mask,
                const unsigned char* __restrict__ kimg,
                const unsigned char* __restrict__ vimg,
                float* __restrict__ out) {
    __shared__ __align__(16) unsigned short smem[2 * 16384];  // 2 x (K 16KB + Vt 16KB)

    const int tid  = threadIdx.x;
    const int lane = tid & 63;
    const int w    = tid >> 6;   // 0..3
    const int l15  = lane & 15;
    const int qd   = lane >> 4;

    const int bh = blockIdx.x >> 4;
    const int s0 = (blockIdx.x & 15) * 128;

    const float* qp = q + (size_t)bh * S_LEN * D_DIM;
    const float* mp = mask + (size_t)bh * S_LEN * S_LEN;
    float*       op = out + (size_t)bh * S_LEN * D_DIM;
    const unsigned char* kb = kimg + (size_t)bh * (2048u * 256u);
    const unsigned char* vb = vimg + (size_t)bh * (32u * 16384u);

    // ---- Q fragments straight from global fp32 ----
    bf16x8 qf[2][4];
#pragma unroll
    for (int sj = 0; sj < 2; ++sj)
#pragma unroll
        for (int kc = 0; kc < 4; ++kc) {
            const float* qq = qp + (size_t)(s0 + 32 * w + 16 * sj + l15) * D_DIM
                            + kc * 32 + qd * 8;
            float4 f0 = *(const float4*)qq, f1 = *(const float4*)(qq + 4);
            union { uint4 u; bf16x8 b; } cv;
            cv.u.x = pack2(f0.x, f0.y); cv.u.y = pack2(f0.z, f0.w);
            cv.u.z = pack2(f1.x, f1.y); cv.u.w = pack2(f1.z, f1.w);
            qf[sj][kc] = cv.b;
        }

    // ---- mask double registers ----
    const float* mbase = mp + (size_t)(s0 + 32 * w + l15) * S_LEN + 4 * qd;
    float4 mcur[4][2], mnxt[4][2];
#pragma unroll
    for (int ti = 0; ti < 4; ++ti)
#pragma unroll
        for (int sj = 0; sj < 2; ++sj)
            mcur[ti][sj] = *(const float4*)(mbase + (size_t)(16 * sj) * S_LEN + 16 * ti);

    // ---- DMA tile 0 into buf 0 ----
    {
        unsigned short* lb = smem;
#pragma unroll
        for (int s = 0; s < 8; ++s) {
            const int seg = w + s * 4;
            const unsigned char* g = (seg < 16) ? (kb + seg * 1024)
                                                : (vb + (seg - 16) * 1024);
            async_cp16(g + lane * 16, (void*)(lb + seg * 512 + lane * 8));
        }
    }
    __syncthreads();

    f32x4 acc_o[2][8];
#pragma unroll
    for (int i = 0; i < 2; ++i)
#pragma unroll
        for (int j = 0; j < 8; ++j) acc_o[i][j] = (f32x4){0.f, 0.f, 0.f, 0.f};

    // bpermute quad-exchange (validated R2)
    const int a0 = ((2 * (qd & 1)) * 16 + l15) * 4;
    const int a1 = a0 + 64;
    const bool hi = (qd >= 2);

    int cur = 0;
    for (int it = 0; it < NIT; ++it) {
        const bool pf = (it + 1 < NIT);
        const int nxt = cur ^ 1;
        const unsigned short* Ks = smem + cur * 16384;
        const unsigned short* Vt = smem + cur * 16384 + 8192;

        // ---- issue DMA for tile it+1 into buf nxt ----
        if (pf) {
            const unsigned char* kt = kb + (size_t)(it + 1) * 16384;
            const unsigned char* vt = vb + (size_t)(it + 1) * 16384;
            unsigned short* lb = smem + nxt * 16384;
#pragma unroll
            for (int s = 0; s < 8; ++s) {
                const int seg = w + s * 4;
                const unsigned char* g = (seg < 16) ? (kt + seg * 1024)
                                                    : (vt + (seg - 16) * 1024);
                async_cp16(g + lane * 16, (void*)(lb + seg * 512 + lane * 8));
            }
            // ---- prefetch mask(it+1): full-iter window ----
            const float* mb = mbase + (size_t)(it + 1) * BK;
#pragma unroll
            for (int ti = 0; ti < 4; ++ti)
#pragma unroll
                for (int sj = 0; sj < 2; ++sj)
                    mnxt[ti][sj] = *(const float4*)(mb + (size_t)(16 * sj) * S_LEN + 16 * ti);
        }

        // ---- S^T = K·Q^T (swizzled b128 reads, conflict-free) ----
        f32x4 acc_s[4][2];
#pragma unroll
        for (int i = 0; i < 4; ++i)
#pragma unroll
            for (int j = 0; j < 2; ++j) acc_s[i][j] = (f32x4){0.f, 0.f, 0.f, 0.f};
#pragma unroll
        for (int kc = 0; kc < 4; ++kc) {
            bf16x8 af[4];
#pragma unroll
            for (int ti = 0; ti < 4; ++ti)
                af[ti] = *(const bf16x8*)&Ks[((16 * ti + l15) << 7) +
                                             (((kc * 4 + qd) ^ l15) << 3)];
#pragma unroll
            for (int ti = 0; ti < 4; ++ti)
#pragma unroll
                for (int sj = 0; sj < 2; ++sj)
                    acc_s[ti][sj] = __builtin_amdgcn_mfma_f32_16x16x32_bf16(
                        af[ti], qf[sj][kc], acc_s[ti][sj], 0, 0, 0);
        }

        // ---- P = S^T ∘ mask -> packed bf16 ----
        int pu[4][2][2];
#pragma unroll
        for (int ti = 0; ti < 4; ++ti)
#pragma unroll
            for (int sj = 0; sj < 2; ++sj) {
                f32x4 sv = acc_s[ti][sj];
                float4 m = mcur[ti][sj];
                pu[ti][sj][0] = (int)pack2(sv[0] * m.x, sv[1] * m.y);
                pu[ti][sj][1] = (int)pack2(sv[2] * m.z, sv[3] * m.w);
            }

        // ---- quad-exchange + O += P·V (swizzled bv reads) ----
#pragma unroll
        for (int kc2 = 0; kc2 < 2; ++kc2) {
            bf16x8 ap[2];
#pragma unroll
            for (int sj = 0; sj < 2; ++sj) {
                const int tA = 2 * kc2, tB = 2 * kc2 + 1;
                int w0a = __builtin_amdgcn_ds_bpermute(a0, pu[tA][sj][0]);
                int w0b = __builtin_amdgcn_ds_bpermute(a0, pu[tB][sj][0]);
                int w1a = __builtin_amdgcn_ds_bpermute(a0, pu[tA][sj][1]);
                int w1b = __builtin_amdgcn_ds_bpermute(a0, pu[tB][sj][1]);
                int w2a = __builtin_amdgcn_ds_bpermute(a1, pu[tA][sj][0]);
                int w2b = __builtin_amdgcn_ds_bpermute(a1, pu[tB][sj][0]);
                int w3a = __builtin_amdgcn_ds_bpermute(a1, pu[tA][sj][1]);
                int w3b = __builtin_amdgcn_ds_bpermute(a1, pu[tB][sj][1]);
                union { i32x4 i; bf16x8 b; } u;
                u.i = (i32x4){hi ? w0b : w0a, hi ? w1b : w1a,
                              hi ? w2b : w2a, hi ? w3b : w3a};
                ap[sj] = u.b;
            }
#pragma unroll
            for (int dj = 0; dj < 8; ++dj) {
                bf16x8 bvv = *(const bf16x8*)&Vt[((16 * dj + l15) << 6) +
                                                 (((kc2 * 4 + qd) ^ (l15 & 7)) << 3)];
#pragma unroll
                for (int sj = 0; sj < 2; ++sj)
                    acc_o[sj][dj] = __builtin_amdgcn_mfma_f32_16x16x32_bf16(
                        ap[sj], bvv, acc_o[sj][dj], 0, 0, 0);
            }
        }

        __syncthreads();  // drains DMA (vmcnt) + guards buffer swap
        if (pf) {
#pragma unroll
            for (int ti = 0; ti < 4; ++ti)
#pragma unroll
                for (int sj = 0; sj < 2; ++sj) mcur[ti][sj] = mnxt[ti][sj];
        }
        cur = nxt;
    }

    // ---- epilogue ----
#pragma unroll
    for (int si = 0; si < 2; ++si)
#pragma unroll
        for (int dj = 0; dj < 8; ++dj)
#pragma unroll
            for (int r = 0; r < 4; ++r) {
                const int srow = s0 + 32 * w + 16 * si + 4 * qd + r;
                op[(size_t)srow * D_DIM + 16 * dj + l15] = acc_o[si][dj][r];
            }
}

extern "C" void kernel_launch(void* const* d_in, const int* in_sizes, int n_in,
                              void* d_out, int out_size, void* d_ws, size_t ws_size,
                              hipStream_t stream) {
    const float* q = (const float*)d_in[0];
    const float* k = (const float*)d_in[1];
    const float* v = (const float*)d_in[2];
    const float* m = (const float*)d_in[3];
    unsigned char* kimg = (unsigned char*)d_ws;
    unsigned char* vimg = kimg + KIMG_BYTES;
    prep<<<dim3(5120), dim3(256), 0, stream>>>(k, v, kimg, vimg);
    fused_main<<<dim3(512), dim3(256), 0, stream>>>(q, m, kimg, vimg, (float*)d_out);
}